// Round 12
// baseline (2076.186 us; speedup 1.0000x reference)
//
#include <hip/hip_runtime.h>

// Two-layer tanh RNN, H=32, B=64, T=16384. Latency-bound sequential scan.
//
// Round-28: R27 (1838 us green, absmax 3.906e-3) with the 16-bpermute
// broadcast replaced by LDS-staged broadcast: 1 ds_write_b32 (even-lo
// lanes deposit packed pair j at stg[pair]; others -> sink) + 4x
// ds_read_b128 (uniform addr). -11 instructions/step. Same-wave DS ops
// execute IN ORDER in the DS pipe, so the read may issue right after the
// write (no fence needed); compiler's fine-grained lgkmcnt pipelines the
// 4 reads against the 16 dots. Bits delivered to hb[] and dot order are
// IDENTICAL to R27 => absmax must be exactly 0.00390625.
// All R27 cuts retained: TSC pre-folded weights/seeds (4-dep tanh),
// uval folded into wave-B seed, cvt_pkrtz pack, unroll 8.

#define T_LEN 16384
#define B_SZ  64
#define NW    (T_LEN / 32)   // 512 windows
#define TSC   2.885390082f   // 2*log2(e)

#if __has_builtin(__builtin_amdgcn_exp2f)
#define EXP2(x) __builtin_amdgcn_exp2f(x)
#else
#define EXP2(x) exp2f(x)
#endif

typedef _Float16 h2 __attribute__((ext_vector_type(2)));

__device__ __forceinline__ float rl(float v, int lane) {
  return __int_as_float(__builtin_amdgcn_readlane(__float_as_int(v), lane));
}

// quad_perm([1,0,3,2]): each lane sees its pair-neighbor's value.
__device__ __forceinline__ float pair_swap(float v) {
  int t = __builtin_amdgcn_update_dpp(0, __float_as_int(v), 0xB1, 0xF, 0xF, true);
  return __int_as_float(t);
}

// tanh with the 2*log2(e) scale PRE-FOLDED into the argument:
// tanh = 1 - 2/(2^v + 1), v = 2*log2(e)*x. 4-dep chain (mul removed).
__device__ __forceinline__ float tanh_pre(float v) {
  float e = EXP2(v);
  return fmaf(-2.f, __builtin_amdgcn_rcpf(e + 1.f), 1.f);
}

#if __has_builtin(__builtin_amdgcn_fdot2)
#define FDOT2(a, b, c) __builtin_amdgcn_fdot2((a), (b), (c), false)
#else
#define FDOT2(a, b, c) \
  fmaf((float)(a).x, (float)(b).x, fmaf((float)(a).y, (float)(b).y, (c)))
#endif

// Pack this lane's state with its pair-neighbor: even lane 2j ends with
// (h[2j], h[2j+1]). DPP on f32 first, then ONE packed convert (RTZ).
__device__ __forceinline__ h2 pack_state(float hcur) {
  float hsw = pair_swap(hcur);
#if __has_builtin(__builtin_amdgcn_cvt_pkrtz)
  return __builtin_bit_cast(h2, __builtin_amdgcn_cvt_pkrtz(hcur, hsw));
#else
  h2 p; p.x = (_Float16)hcur; p.y = (_Float16)hsw; return p;
#endif
}

// LDS-staged broadcast: deposit this lane's packed pair (even-lo lanes at
// stg[pair j=m/2], others -> sink), then read all 16 pairs back via 4x
// b128 at a uniform address. Same-wave DS in-order => RAW safe, no fence.
#define STAGE_BCAST(hb, hpk)                                   \
  do {                                                         \
    *wstage = __builtin_bit_cast(int, (hpk));                  \
    _Pragma("unroll")                                          \
    for (int k_ = 0; k_ < 4; ++k_) {                           \
      float4 q_ = ((const float4*)stgw)[k_];                   \
      (hb)[4 * k_ + 0] = __builtin_bit_cast(h2, q_.x);         \
      (hb)[4 * k_ + 1] = __builtin_bit_cast(h2, q_.y);         \
      (hb)[4 * k_ + 2] = __builtin_bit_cast(h2, q_.z);         \
      (hb)[4 * k_ + 3] = __builtin_bit_cast(h2, q_.w);         \
    }                                                          \
  } while (0)

// 32-term dot via 16 dot2, 4 accumulators (depth 4) + 2-level tree.
__device__ __forceinline__ float dot32h(const h2* w, const h2* hb, float seed) {
  float a0 = seed, a1 = 0.f, a2 = 0.f, a3 = 0.f;
#pragma unroll
  for (int j = 0; j < 4; ++j) {
    a0 = FDOT2(w[4 * j + 0], hb[4 * j + 0], a0);
    a1 = FDOT2(w[4 * j + 1], hb[4 * j + 1], a1);
    a2 = FDOT2(w[4 * j + 2], hb[4 * j + 2], a2);
    a3 = FDOT2(w[4 * j + 3], hb[4 * j + 3], a3);
  }
  return (a0 + a1) + (a2 + a3);
}

__global__ __launch_bounds__(128, 1) void rnn2_kernel(
    const float* __restrict__ x,    const float* __restrict__ hs,
    const float* __restrict__ Wih0, const float* __restrict__ Whh0,
    const float* __restrict__ bih0, const float* __restrict__ bhh0,
    const float* __restrict__ Wih1, const float* __restrict__ Whh1,
    const float* __restrict__ bih1, const float* __restrict__ bhh1,
    const float* __restrict__ Wout, const float* __restrict__ bout,
    float* __restrict__ out)
{
  __shared__ __align__(16) float uwin[2][1024];   // A->B; slot t2*32 + row
  __shared__ __align__(16) float scratch[1024];   // sink (never read)
  __shared__ __align__(16) float stg[2][16];      // per-wave 64B stage

  const int  tid = (int)threadIdx.x;
  const int  wv  = tid >> 6;            // 0 = wave A (h0), 1 = wave B (h1)
  const int  m   = tid & 63;
  const int  r   = m & 31;              // row owned by this lane
  const bool hi  = (m >= 32);           // secondary-matrix half
  const int  b   = (int)blockIdx.x;

  // Per-lane full 32-float row, packed to 16 f16 pairs, with the tanh
  // input scale TSC pre-folded where the dot feeds tanh (or the published
  // u, which wave B consumes as a pre-scaled tanh seed):
  //  A: lo = TSC*Whh0[r], hi = TSC*Wih1[r]   (published u = TSC*u_raw)
  //  B: lo = TSC*Whh1[r], hi = Wout (raw; feeds out, not tanh)
  const float* pw = (wv == 0) ? (hi ? (Wih1 + r * 32) : (Whh0 + r * 32))
                              : (hi ? Wout : (Whh1 + r * 32));
  const float wsc = (wv == 0) ? TSC : (hi ? 1.f : TSC);
  h2 w[16];
#pragma unroll
  for (int k = 0; k < 8; ++k) {
    float4 q = ((const float4*)pw)[k];
    w[2 * k].x     = (_Float16)(q.x * wsc);
    w[2 * k].y     = (_Float16)(q.y * wsc);
    w[2 * k + 1].x = (_Float16)(q.z * wsc);
    w[2 * k + 1].y = (_Float16)(q.w * wsc);
  }

  float xw = 0.f, binv = 0.f;
  if (wv == 0) {
    if (hi) binv = TSC * (bih1[r] + bhh1[r]);    // u seed: TSC*b1
    else  { binv = TSC * (bih0[r] + bhh0[r]); xw = TSC * Wih0[r]; }
  }
  const float bo = bout[0];

  // State register: lane k (k<32) holds h[k] in f32 (raw, unscaled). Hi
  // lanes carry garbage copies; pack_state/stage read even lanes 0..30.
  float hcur = (wv == 0) ? hs[b * 32 + r] : hs[2048 + b * 32 + r];

  // Stage pointers (loop-invariant): even-lo lanes deposit pair m/2.
  const float* stgw = &stg[wv][0];
  int* wstage = (!(m & 1) && !hi) ? (int*)&stg[wv][m >> 1]
                                  : (int*)&scratch[m];

  // Wave A publish pointers: hi lanes -> uwin row r, lo lanes -> scratch.
  float* up0 = hi ? &uwin[0][r] : &scratch[r];
  float* up1 = hi ? &uwin[1][r] : &scratch[r];

  const float* xb   = x + (size_t)b * T_LEN;
  float*       outp = out + (size_t)b * T_LEN;       // outs[b*T + t]
  float*       hf   = out + (size_t)B_SZ * T_LEN;    // h_final [2,B,H]

  float obuf = 0.f;
  float xcur = 0.f;
  if (wv == 0) xcur = xb[m];            // window 0 chunk (lanes 0..31 used)

  for (int wdx = 0; wdx <= NW; ++wdx) {
    if (wv == 0) {
      if (wdx < NW) {
        // Prefetch next window's x chunk; consumed 32 steps from now.
        float xnext = 0.f;
        if (wdx + 1 < NW) {
          int xi = 32 * (wdx + 1) + m; if (xi > T_LEN - 1) xi = T_LEN - 1;
          xnext = xb[xi];
        }
        float* up = (wdx & 1) ? up1 : up0;
#pragma unroll 8
        for (int t2 = 0; t2 < 32; ++t2) {
          h2 hpk = pack_state(hcur);        // h0n(t-1) packed pairs
          h2 hb[16];
          STAGE_BCAST(hb, hpk);             // 1 write + 4 b128 reads
          float xv   = rl(xcur, t2);        // x(t)   (off-chain)
          float seed = fmaf(xv, xw, binv);  // lo: TSC*(x*W+b0); hi: TSC*b1
          float acc  = dot32h(w, hb, seed); // lo: tanh arg; hi: TSC*u(t-1)
          up[t2 * 32] = acc;                // hi publishes u; lo -> scratch
          hcur = tanh_pre(acc);             // lo lanes: h0n(t)
        }
        xcur = xnext;
      }
    } else {
      if (wdx >= 1) {
        const int wb = wdx - 1;             // steps t = 32*wb-1 .. 32*wb+30
        const float* ub = &uwin[wb & 1][r];
        float uval = ub[0];                 // TSC*u(32*wb-1)
#pragma unroll 8
        for (int t2 = 0; t2 < 32; ++t2) {
          const int t = 32 * wb - 1 + t2;
          h2 hpk = pack_state(hcur);        // h1n(t-1) packed pairs
          h2 hb[16];
          STAGE_BCAST(hb, hpk);             // 1 write + 4 b128 reads
          float sB  = hi ? 0.f : uval;      // uval folded into seed
          float acc = dot32h(w, hb, sB);    // lo: tanh arg; hi: out(t-1)-bo
          float unext = ub[((t2 + 1) & 31) * 32];  // pipelined u-read
          float h1n = tanh_pre(acc);
          obuf = (m == 32 + t2) ? acc : obuf;      // hi lane t2: out(t-1)-bo
          if (t >= 0) hcur = h1n;           // uniform guard (skips wb=0,t2=0)
          uval = unext;
        }
        const int idx = 32 * wb - 2 + r;    // hi lane 32+k holds out(32wb-2+k)
        if (hi && idx >= 0) outp[idx] = obuf + bo;   // coalesced store
      }
    }
    __syncthreads();   // window handoff (uwin parity swap)
  }

  // Epilogue 1 (wave A): publish TSC*u(T-1) from h0n(T-1); h_final L0.
  if (wv == 0) {
    h2 hpk = pack_state(hcur);              // h0n(T-1)
    h2 hb[16];
    STAGE_BCAST(hb, hpk);
    float acc = dot32h(w, hb, binv);        // hi: TSC*(b1 + Wih1.h0n(T-1))
    if (hi) uwin[0][r] = acc;
    else    hf[b * 32 + r] = hcur;          // h_final layer 0 (full f32)
  }
  __syncthreads();

  // Epilogue 2 (wave B): h1n(T-1), out(T-2), out(T-1), h_final L1.
  if (wv == 1) {
    float uT = uwin[0][r];                  // TSC*u(T-1)
    h2 hpk = pack_state(hcur);              // h1n(T-2)
    h2 hb[16];
    STAGE_BCAST(hb, hpk);
    float acc = dot32h(w, hb, hi ? 0.f : uT);
    if (m == 32) outp[T_LEN - 2] = acc + bo;      // Wout . h1n(T-2) (raw hi)
    float h1T = tanh_pre(acc);              // valid in lo lanes
    h2 hpk2 = pack_state(h1T);              // h1n(T-1)
    h2 hb2[16];
    STAGE_BCAST(hb2, hpk2);
    float acc2 = dot32h(w, hb2, 0.f);
    if (m == 32) outp[T_LEN - 1] = acc2 + bo;     // Wout . h1n(T-1)
    if (!hi) hf[2048 + b * 32 + r] = h1T;   // h_final layer 1 (full f32)
  }
}

extern "C" void kernel_launch(void* const* d_in, const int* in_sizes, int n_in,
                              void* d_out, int out_size, void* d_ws, size_t ws_size,
                              hipStream_t stream) {
  rnn2_kernel<<<dim3(B_SZ), dim3(128), 0, stream>>>(
      (const float*)d_in[0],  (const float*)d_in[1],  (const float*)d_in[2],
      (const float*)d_in[3],  (const float*)d_in[4],  (const float*)d_in[5],
      (const float*)d_in[6],  (const float*)d_in[7],  (const float*)d_in[8],
      (const float*)d_in[9],  (const float*)d_in[10], (const float*)d_in[11],
      (float*)d_out);
}

// Round 13
// 1974.375 us; speedup vs baseline: 1.0516x; 1.0516x over previous
//
#include <hip/hip_runtime.h>

// Two-layer tanh RNN, H=32, B=64, T=16384. Latency-bound sequential scan.
//
// Round-29: hybrid broadcast = R27's bpermute (pairs 0-7) + R28's LDS stage
// (pairs 8-15). Cost model (fits R18/R22/R25/R26/R27/R28): transport ops
// occupy ~8 cyc each on their pipe; 16/step = ~half the step. R28 proved
// the LDS path's bits are exact but paid the write->read RAW as raw stall
// (nothing between them). Here the 8 bpermutes ARE the separation: DS pipe
// is in-order within a wave, so write -> 8 bperms -> 2x ds_read_b128 means
// the reads execute long after the write completes, and their data lands
// during dots 0-7. Transport ~96 cyc vs 128. Bits + dot order identical to
// R27/R28 => absmax must be exactly 0.00390625.
// All R27 cuts retained: TSC pre-folded weights/seeds (4-dep tanh), uval
// folded into wave-B seed, cvt_pkrtz pack, unroll 8.

#define T_LEN 16384
#define B_SZ  64
#define NW    (T_LEN / 32)   // 512 windows
#define TSC   2.885390082f   // 2*log2(e)

#if __has_builtin(__builtin_amdgcn_exp2f)
#define EXP2(x) __builtin_amdgcn_exp2f(x)
#else
#define EXP2(x) exp2f(x)
#endif

typedef _Float16 h2 __attribute__((ext_vector_type(2)));

__device__ __forceinline__ float rl(float v, int lane) {
  return __int_as_float(__builtin_amdgcn_readlane(__float_as_int(v), lane));
}

// Wave-uniform broadcast via the LDS crossbar: every lane pulls the pack
// register of lane (byteaddr>>2). No LDS storage touched; DS pipe op.
__device__ __forceinline__ h2 bperm_h2(int byteaddr, h2 v) {
  int o = __builtin_amdgcn_ds_bpermute(byteaddr, __builtin_bit_cast(int, v));
  return __builtin_bit_cast(h2, o);
}

// quad_perm([1,0,3,2]): each lane sees its pair-neighbor's value.
__device__ __forceinline__ float pair_swap(float v) {
  int t = __builtin_amdgcn_update_dpp(0, __float_as_int(v), 0xB1, 0xF, 0xF, true);
  return __int_as_float(t);
}

// tanh with the 2*log2(e) scale PRE-FOLDED into the argument:
// tanh = 1 - 2/(2^v + 1), v = 2*log2(e)*x. 4-dep chain (mul removed).
__device__ __forceinline__ float tanh_pre(float v) {
  float e = EXP2(v);
  return fmaf(-2.f, __builtin_amdgcn_rcpf(e + 1.f), 1.f);
}

#if __has_builtin(__builtin_amdgcn_fdot2)
#define FDOT2(a, b, c) __builtin_amdgcn_fdot2((a), (b), (c), false)
#else
#define FDOT2(a, b, c) \
  fmaf((float)(a).x, (float)(b).x, fmaf((float)(a).y, (float)(b).y, (c)))
#endif

// Pack this lane's state with its pair-neighbor: even lane 2j ends with
// (h[2j], h[2j+1]). DPP on f32 first, then ONE packed convert (RTZ).
__device__ __forceinline__ h2 pack_state(float hcur) {
  float hsw = pair_swap(hcur);
#if __has_builtin(__builtin_amdgcn_cvt_pkrtz)
  return __builtin_bit_cast(h2, __builtin_amdgcn_cvt_pkrtz(hcur, hsw));
#else
  h2 p; p.x = (_Float16)hcur; p.y = (_Float16)hsw; return p;
#endif
}

// Hybrid broadcast: ds_write of this lane's pack FIRST (starts RAW clock;
// even-lo lanes -> stg[m/2], others -> sink), 8 bpermutes for pairs 0-7
// (separation + early dot operands), then 2x uniform ds_read_b128 for
// pairs 8-15 (in-order DS pipe => write long complete; data lands under
// dots 0-7).
#define SPLIT_BCAST(hb, hpk)                                   \
  do {                                                         \
    *wstage = __builtin_bit_cast(int, (hpk));                  \
    _Pragma("unroll")                                          \
    for (int j_ = 0; j_ < 8; ++j_)                             \
      (hb)[j_] = bperm_h2(8 * j_, (hpk));                      \
    _Pragma("unroll")                                          \
    for (int k_ = 2; k_ < 4; ++k_) {                           \
      float4 q_ = ((const float4*)stgw)[k_];                   \
      (hb)[4 * k_ + 0] = __builtin_bit_cast(h2, q_.x);         \
      (hb)[4 * k_ + 1] = __builtin_bit_cast(h2, q_.y);         \
      (hb)[4 * k_ + 2] = __builtin_bit_cast(h2, q_.z);         \
      (hb)[4 * k_ + 3] = __builtin_bit_cast(h2, q_.w);         \
    }                                                          \
  } while (0)

// 32-term dot via 16 dot2, 4 accumulators (depth 4) + 2-level tree.
__device__ __forceinline__ float dot32h(const h2* w, const h2* hb, float seed) {
  float a0 = seed, a1 = 0.f, a2 = 0.f, a3 = 0.f;
#pragma unroll
  for (int j = 0; j < 4; ++j) {
    a0 = FDOT2(w[4 * j + 0], hb[4 * j + 0], a0);
    a1 = FDOT2(w[4 * j + 1], hb[4 * j + 1], a1);
    a2 = FDOT2(w[4 * j + 2], hb[4 * j + 2], a2);
    a3 = FDOT2(w[4 * j + 3], hb[4 * j + 3], a3);
  }
  return (a0 + a1) + (a2 + a3);
}

__global__ __launch_bounds__(128, 1) void rnn2_kernel(
    const float* __restrict__ x,    const float* __restrict__ hs,
    const float* __restrict__ Wih0, const float* __restrict__ Whh0,
    const float* __restrict__ bih0, const float* __restrict__ bhh0,
    const float* __restrict__ Wih1, const float* __restrict__ Whh1,
    const float* __restrict__ bih1, const float* __restrict__ bhh1,
    const float* __restrict__ Wout, const float* __restrict__ bout,
    float* __restrict__ out)
{
  __shared__ __align__(16) float uwin[2][1024];   // A->B; slot t2*32 + row
  __shared__ __align__(16) float scratch[1024];   // sink (never read)
  __shared__ __align__(16) float stg[2][16];      // per-wave 64B stage

  const int  tid = (int)threadIdx.x;
  const int  wv  = tid >> 6;            // 0 = wave A (h0), 1 = wave B (h1)
  const int  m   = tid & 63;
  const int  r   = m & 31;              // row owned by this lane
  const bool hi  = (m >= 32);           // secondary-matrix half
  const int  b   = (int)blockIdx.x;

  // Per-lane full 32-float row, packed to 16 f16 pairs, with the tanh
  // input scale TSC pre-folded where the dot feeds tanh (or the published
  // u, which wave B consumes as a pre-scaled tanh seed):
  //  A: lo = TSC*Whh0[r], hi = TSC*Wih1[r]   (published u = TSC*u_raw)
  //  B: lo = TSC*Whh1[r], hi = Wout (raw; feeds out, not tanh)
  const float* pw = (wv == 0) ? (hi ? (Wih1 + r * 32) : (Whh0 + r * 32))
                              : (hi ? Wout : (Whh1 + r * 32));
  const float wsc = (wv == 0) ? TSC : (hi ? 1.f : TSC);
  h2 w[16];
#pragma unroll
  for (int k = 0; k < 8; ++k) {
    float4 q = ((const float4*)pw)[k];
    w[2 * k].x     = (_Float16)(q.x * wsc);
    w[2 * k].y     = (_Float16)(q.y * wsc);
    w[2 * k + 1].x = (_Float16)(q.z * wsc);
    w[2 * k + 1].y = (_Float16)(q.w * wsc);
  }

  float xw = 0.f, binv = 0.f;
  if (wv == 0) {
    if (hi) binv = TSC * (bih1[r] + bhh1[r]);    // u seed: TSC*b1
    else  { binv = TSC * (bih0[r] + bhh0[r]); xw = TSC * Wih0[r]; }
  }
  const float bo = bout[0];

  // State register: lane k (k<32) holds h[k] in f32 (raw, unscaled). Hi
  // lanes carry garbage copies; pack_state/transport read even lanes 0..30.
  float hcur = (wv == 0) ? hs[b * 32 + r] : hs[2048 + b * 32 + r];

  // Stage pointers (loop-invariant): even-lo lanes deposit pair m/2.
  const float* stgw = &stg[wv][0];
  int* wstage = (!(m & 1) && !hi) ? (int*)&stg[wv][m >> 1]
                                  : (int*)&scratch[m];

  // Wave A publish pointers: hi lanes -> uwin row r, lo lanes -> scratch.
  float* up0 = hi ? &uwin[0][r] : &scratch[r];
  float* up1 = hi ? &uwin[1][r] : &scratch[r];

  const float* xb   = x + (size_t)b * T_LEN;
  float*       outp = out + (size_t)b * T_LEN;       // outs[b*T + t]
  float*       hf   = out + (size_t)B_SZ * T_LEN;    // h_final [2,B,H]

  float obuf = 0.f;
  float xcur = 0.f;
  if (wv == 0) xcur = xb[m];            // window 0 chunk (lanes 0..31 used)

  for (int wdx = 0; wdx <= NW; ++wdx) {
    if (wv == 0) {
      if (wdx < NW) {
        // Prefetch next window's x chunk; consumed 32 steps from now.
        float xnext = 0.f;
        if (wdx + 1 < NW) {
          int xi = 32 * (wdx + 1) + m; if (xi > T_LEN - 1) xi = T_LEN - 1;
          xnext = xb[xi];
        }
        float* up = (wdx & 1) ? up1 : up0;
#pragma unroll 8
        for (int t2 = 0; t2 < 32; ++t2) {
          h2 hpk = pack_state(hcur);        // h0n(t-1) packed pairs
          h2 hb[16];
          SPLIT_BCAST(hb, hpk);             // write + 8 bperm + 2 b128
          float xv   = rl(xcur, t2);        // x(t)   (off-chain)
          float seed = fmaf(xv, xw, binv);  // lo: TSC*(x*W+b0); hi: TSC*b1
          float acc  = dot32h(w, hb, seed); // lo: tanh arg; hi: TSC*u(t-1)
          up[t2 * 32] = acc;                // hi publishes u; lo -> scratch
          hcur = tanh_pre(acc);             // lo lanes: h0n(t)
        }
        xcur = xnext;
      }
    } else {
      if (wdx >= 1) {
        const int wb = wdx - 1;             // steps t = 32*wb-1 .. 32*wb+30
        const float* ub = &uwin[wb & 1][r];
        float uval = ub[0];                 // TSC*u(32*wb-1)
#pragma unroll 8
        for (int t2 = 0; t2 < 32; ++t2) {
          const int t = 32 * wb - 1 + t2;
          h2 hpk = pack_state(hcur);        // h1n(t-1) packed pairs
          h2 hb[16];
          SPLIT_BCAST(hb, hpk);             // write + 8 bperm + 2 b128
          float sB  = hi ? 0.f : uval;      // uval folded into seed
          float acc = dot32h(w, hb, sB);    // lo: tanh arg; hi: out(t-1)-bo
          float unext = ub[((t2 + 1) & 31) * 32];  // pipelined u-read
          float h1n = tanh_pre(acc);
          obuf = (m == 32 + t2) ? acc : obuf;      // hi lane t2: out(t-1)-bo
          if (t >= 0) hcur = h1n;           // uniform guard (skips wb=0,t2=0)
          uval = unext;
        }
        const int idx = 32 * wb - 2 + r;    // hi lane 32+k holds out(32wb-2+k)
        if (hi && idx >= 0) outp[idx] = obuf + bo;   // coalesced store
      }
    }
    __syncthreads();   // window handoff (uwin parity swap)
  }

  // Epilogue 1 (wave A): publish TSC*u(T-1) from h0n(T-1); h_final L0.
  if (wv == 0) {
    h2 hpk = pack_state(hcur);              // h0n(T-1)
    h2 hb[16];
    SPLIT_BCAST(hb, hpk);
    float acc = dot32h(w, hb, binv);        // hi: TSC*(b1 + Wih1.h0n(T-1))
    if (hi) uwin[0][r] = acc;
    else    hf[b * 32 + r] = hcur;          // h_final layer 0 (full f32)
  }
  __syncthreads();

  // Epilogue 2 (wave B): h1n(T-1), out(T-2), out(T-1), h_final L1.
  if (wv == 1) {
    float uT = uwin[0][r];                  // TSC*u(T-1)
    h2 hpk = pack_state(hcur);              // h1n(T-2)
    h2 hb[16];
    SPLIT_BCAST(hb, hpk);
    float acc = dot32h(w, hb, hi ? 0.f : uT);
    if (m == 32) outp[T_LEN - 2] = acc + bo;      // Wout . h1n(T-2) (raw hi)
    float h1T = tanh_pre(acc);              // valid in lo lanes
    h2 hpk2 = pack_state(h1T);              // h1n(T-1)
    h2 hb2[16];
    SPLIT_BCAST(hb2, hpk2);
    float acc2 = dot32h(w, hb2, 0.f);
    if (m == 32) outp[T_LEN - 1] = acc2 + bo;     // Wout . h1n(T-1)
    if (!hi) hf[2048 + b * 32 + r] = h1T;   // h_final layer 1 (full f32)
  }
}

extern "C" void kernel_launch(void* const* d_in, const int* in_sizes, int n_in,
                              void* d_out, int out_size, void* d_ws, size_t ws_size,
                              hipStream_t stream) {
  rnn2_kernel<<<dim3(B_SZ), dim3(128), 0, stream>>>(
      (const float*)d_in[0],  (const float*)d_in[1],  (const float*)d_in[2],
      (const float*)d_in[3],  (const float*)d_in[4],  (const float*)d_in[5],
      (const float*)d_in[6],  (const float*)d_in[7],  (const float*)d_in[8],
      (const float*)d_in[9],  (const float*)d_in[10], (const float*)d_in[11],
      (float*)d_out);
}